// Round 1
// baseline (540.246 us; speedup 1.0000x reference)
//
#include <hip/hip_runtime.h>
#include <hip/hip_bf16.h>
#include <math.h>

#define D_IN 1024
#define D_HID 256
#define D_CLS 128
#define N_CLASSES 4
#define N_INST 50000

#define ROWS 64
#define NBLK ((N_INST + ROWS - 1) / ROWS)   // 782
#define NB2 64
#define CHUNK ((NBLK + NB2 - 1) / NB2)      // 13
#define NEG_BIG (-1e30f)

typedef __attribute__((ext_vector_type(8))) short bf16x8;
typedef __attribute__((ext_vector_type(4))) float f32x4;

// ---------------- weight convert + transpose (fp32 -> bf16, W^T layout) ----------------
__global__ void convert_weights(const float* __restrict__ w1, const float* __restrict__ wv,
                                const float* __restrict__ wa, const float* __restrict__ wb,
                                __hip_bfloat16* __restrict__ w1t, __hip_bfloat16* __restrict__ wvt,
                                __hip_bfloat16* __restrict__ wat, __hip_bfloat16* __restrict__ wbt) {
    int idx = blockIdx.x * 256 + threadIdx.x;
    if (idx < D_IN * D_HID) {
        int k = idx >> 8;          // row of W (1024)
        int n = idx & 255;         // col of W (256)
        w1t[(size_t)n * D_IN + k] = __float2bfloat16(w1[idx]);
    }
    if (idx < D_HID * D_HID) {
        int k = idx >> 8, n = idx & 255;
        wvt[n * D_HID + k] = __float2bfloat16(wv[idx]);
        wat[n * D_HID + k] = __float2bfloat16(wa[idx]);
        wbt[n * D_HID + k] = __float2bfloat16(wb[idx]);
    }
}

// 256x256 GEMM stage from LDS tile (A) x global bf16 W^T (B) -> acc
// A-frag: lane l holds S[rt*16 + (l&15)][ks*32 + (l>>4)*8 + j], j=0..7
// B-frag: lane l holds Wt[n][k] = W[k][n] with n = base + (l&15), k = ks*32 + (l>>4)*8 + j
__device__ __forceinline__ void gemm256(const __hip_bfloat16 (*S)[264],
                                        const __hip_bfloat16* __restrict__ Wt,
                                        int wave, int quad, int l16, f32x4 acc[4][4]) {
    f32x4 zero = {0.f, 0.f, 0.f, 0.f};
#pragma unroll
    for (int i = 0; i < 4; i++)
#pragma unroll
        for (int j = 0; j < 4; j++) acc[i][j] = zero;
#pragma unroll
    for (int ks = 0; ks < 8; ks++) {
        bf16x8 af[4];
#pragma unroll
        for (int rt = 0; rt < 4; rt++)
            af[rt] = *(const bf16x8*)&S[rt * 16 + l16][ks * 32 + quad * 8];
#pragma unroll
        for (int ct = 0; ct < 4; ct++) {
            bf16x8 bf = *(const bf16x8*)(Wt + (size_t)(wave * 64 + ct * 16 + l16) * D_HID + ks * 32 + quad * 8);
#pragma unroll
            for (int rt = 0; rt < 4; rt++)
                acc[rt][ct] = __builtin_amdgcn_mfma_f32_16x16x32_bf16(af[rt], bf, acc[rt][ct], 0, 0, 0);
        }
    }
}

// ---------------- main fused kernel: 64 rows per block ----------------
__launch_bounds__(256, 2)
__global__ void mcat_main(const float* __restrict__ xp,
                          const __hip_bfloat16* __restrict__ w1t, const float* __restrict__ b1,
                          const __hip_bfloat16* __restrict__ wvt, const float* __restrict__ bv,
                          const __hip_bfloat16* __restrict__ wat, const float* __restrict__ ba,
                          const __hip_bfloat16* __restrict__ wbt, const float* __restrict__ bb,
                          const float* __restrict__ acw, const float* __restrict__ acb,
                          float* __restrict__ partials) {
    __shared__ __hip_bfloat16 Xs[ROWS][72];    // stride 36 dw == 4 mod 32 -> 2-way (free)
    __shared__ __hip_bfloat16 Hs[ROWS][264];   // h, then a, then g=a*b
    __shared__ __hip_bfloat16 Vs[ROWS][264];   // v (fused)
    __shared__ float Apart[4][ROWS];
    __shared__ float ExpW[ROWS];

    const int tid  = threadIdx.x;
    const int wave = tid >> 6;
    const int lane = tid & 63;
    const int quad = lane >> 4;
    const int l16  = lane & 15;
    const int row0 = blockIdx.x * ROWS;

    f32x4 acc[4][4];
    f32x4 zero = {0.f, 0.f, 0.f, 0.f};
#pragma unroll
    for (int i = 0; i < 4; i++)
#pragma unroll
        for (int j = 0; j < 4; j++) acc[i][j] = zero;

    // ---- stage 1: h = relu(X @ W1 + b1), K = 1024 in chunks of 64 ----
    for (int kc = 0; kc < D_IN; kc += 64) {
#pragma unroll
        for (int i = 0; i < 4; i++) {
            int lin = (i << 8) + tid;
            int r = lin >> 4;
            int c4 = (lin & 15) << 2;
            int grow = row0 + r;
            float4 xv = {0.f, 0.f, 0.f, 0.f};
            if (grow < N_INST) xv = *(const float4*)(xp + (size_t)grow * D_IN + kc + c4);
            Xs[r][c4 + 0] = __float2bfloat16(xv.x);
            Xs[r][c4 + 1] = __float2bfloat16(xv.y);
            Xs[r][c4 + 2] = __float2bfloat16(xv.z);
            Xs[r][c4 + 3] = __float2bfloat16(xv.w);
        }
        __syncthreads();
#pragma unroll
        for (int ks = 0; ks < 2; ks++) {
            bf16x8 af[4];
#pragma unroll
            for (int rt = 0; rt < 4; rt++)
                af[rt] = *(const bf16x8*)&Xs[rt * 16 + l16][ks * 32 + quad * 8];
#pragma unroll
            for (int ct = 0; ct < 4; ct++) {
                bf16x8 bf = *(const bf16x8*)(w1t + (size_t)(wave * 64 + ct * 16 + l16) * D_IN + kc + ks * 32 + quad * 8);
#pragma unroll
                for (int rt = 0; rt < 4; rt++)
                    acc[rt][ct] = __builtin_amdgcn_mfma_f32_16x16x32_bf16(af[rt], bf, acc[rt][ct], 0, 0, 0);
            }
        }
        __syncthreads();
    }
    // epilogue: +bias, relu, -> Hs (C/D map: col=lane&15, row=quad*4+reg)
#pragma unroll
    for (int ct = 0; ct < 4; ct++) {
        int col = wave * 64 + ct * 16 + l16;
        float bias = b1[col];
#pragma unroll
        for (int rt = 0; rt < 4; rt++)
#pragma unroll
            for (int r = 0; r < 4; r++) {
                int row = rt * 16 + quad * 4 + r;
                float h = acc[rt][ct][r] + bias;
                Hs[row][col] = __float2bfloat16(fmaxf(h, 0.f));
            }
    }
    __syncthreads();

    // ---- stage 2: v = h @ Wv + bv -> Vs ----
    gemm256(Hs, wvt, wave, quad, l16, acc);
#pragma unroll
    for (int ct = 0; ct < 4; ct++) {
        int col = wave * 64 + ct * 16 + l16;
        float bias = bv[col];
#pragma unroll
        for (int rt = 0; rt < 4; rt++)
#pragma unroll
            for (int r = 0; r < 4; r++) {
                int row = rt * 16 + quad * 4 + r;
                Vs[row][col] = __float2bfloat16(acc[rt][ct][r] + bias);
            }
    }
    __syncthreads();   // Hs reads done; Vs ready

    // ---- stage 3a: a = tanh(v @ Wa + ba) -> Hs ----
    gemm256(Vs, wat, wave, quad, l16, acc);
#pragma unroll
    for (int ct = 0; ct < 4; ct++) {
        int col = wave * 64 + ct * 16 + l16;
        float bias = ba[col];
#pragma unroll
        for (int rt = 0; rt < 4; rt++)
#pragma unroll
            for (int r = 0; r < 4; r++) {
                int row = rt * 16 + quad * 4 + r;
                Hs[row][col] = __float2bfloat16(tanhf(acc[rt][ct][r] + bias));
            }
    }
    // no barrier needed: stage 3b reads/writes only its own (row,col) cells

    // ---- stage 3b: g = a * sigmoid(v @ Wb + bb) -> Hs (in place) ----
    gemm256(Vs, wbt, wave, quad, l16, acc);
#pragma unroll
    for (int ct = 0; ct < 4; ct++) {
        int col = wave * 64 + ct * 16 + l16;
        float bias = bb[col];
#pragma unroll
        for (int rt = 0; rt < 4; rt++)
#pragma unroll
            for (int r = 0; r < 4; r++) {
                int row = rt * 16 + quad * 4 + r;
                float bval = 1.f / (1.f + __expf(-(acc[rt][ct][r] + bias)));
                float aval = __bfloat162float(Hs[row][col]);
                Hs[row][col] = __float2bfloat16(aval * bval);
            }
    }
    __syncthreads();

    // ---- stage 4: A_n = g_n . ac_w + ac_b ----
    {
        int r = tid & 63;
        int dg = tid >> 6;
        float s = 0.f;
#pragma unroll 8
        for (int d = 0; d < 64; d++) {
            int col = dg * 64 + d;
            s += __bfloat162float(Hs[r][col]) * acw[col];
        }
        Apart[dg][r] = s;
    }
    __syncthreads();

    // ---- stage 5: block-local online-softmax partials ----
    if (tid < 64) {
        bool valid = (row0 + tid) < N_INST;
        float A = Apart[0][tid] + Apart[1][tid] + Apart[2][tid] + Apart[3][tid] + acb[0];
        if (!valid) A = NEG_BIG;
        float m = A;
#pragma unroll
        for (int off = 32; off > 0; off >>= 1) m = fmaxf(m, __shfl_xor(m, off));
        float e = valid ? __expf(A - m) : 0.f;
        ExpW[tid] = e;
        float ssum = e;
#pragma unroll
        for (int off = 32; off > 0; off >>= 1) ssum += __shfl_xor(ssum, off);
        if (tid == 0) {
            partials[(size_t)blockIdx.x * 258 + 0] = m;
            partials[(size_t)blockIdx.x * 258 + 1] = ssum;
        }
    }
    __syncthreads();
    {
        float p = 0.f;
#pragma unroll 8
        for (int n = 0; n < 64; n++)
            p += ExpW[n] * __bfloat162float(Vs[n][tid]);
        partials[(size_t)blockIdx.x * 258 + 2 + tid] = p;
    }
}

// ---------------- finalize level 1: 782 partials -> 64 ----------------
__global__ void mcat_fin_a(const float* __restrict__ p1, float* __restrict__ p2) {
    __shared__ float sm[1];
    int g = blockIdx.x, tid = threadIdx.x;
    int lo = g * CHUNK;
    int hi = lo + CHUNK; if (hi > NBLK) hi = NBLK;
    if (tid < 64) {
        float m = NEG_BIG;
        if (lo + tid < hi) m = p1[(size_t)(lo + tid) * 258];
#pragma unroll
        for (int off = 32; off > 0; off >>= 1) m = fmaxf(m, __shfl_xor(m, off));
        if (tid == 0) sm[0] = m;
    }
    __syncthreads();
    float M = sm[0];
    float p = 0.f, sacc = 0.f;
    for (int b = lo; b < hi; b++) {
        float sc = __expf(p1[(size_t)b * 258] - M);
        sacc += sc * p1[(size_t)b * 258 + 1];
        p += sc * p1[(size_t)b * 258 + 2 + tid];
    }
    if (tid == 0) {
        p2[(size_t)g * 258 + 0] = M;
        p2[(size_t)g * 258 + 1] = sacc;
    }
    p2[(size_t)g * 258 + 2 + tid] = p;
}

// ---------------- finalize level 2: 64 partials -> pooled -> classifier ----------------
__global__ void mcat_fin_b(const float* __restrict__ p2,
                           const float* __restrict__ c1w, const float* __restrict__ c1b,
                           const float* __restrict__ c2w, const float* __restrict__ c2b,
                           float* __restrict__ out) {
    __shared__ float sm[2];
    __shared__ float sc[NB2];
    __shared__ float pooled[D_HID];
    __shared__ float r1[D_CLS];
    int tid = threadIdx.x;
    if (tid < 64) {
        float m = p2[(size_t)tid * 258];
#pragma unroll
        for (int off = 32; off > 0; off >>= 1) m = fmaxf(m, __shfl_xor(m, off));
        if (tid == 0) sm[0] = m;
    }
    __syncthreads();
    float M = sm[0];
    if (tid < 64) {
        float s = __expf(p2[(size_t)tid * 258] - M);
        sc[tid] = s;
        float Ssum = s * p2[(size_t)tid * 258 + 1];
#pragma unroll
        for (int off = 32; off > 0; off >>= 1) Ssum += __shfl_xor(Ssum, off);
        if (tid == 0) sm[1] = Ssum;
    }
    __syncthreads();
    float S = sm[1];
    float p = 0.f;
#pragma unroll 8
    for (int b = 0; b < NB2; b++)
        p += sc[b] * p2[(size_t)b * 258 + 2 + tid];
    pooled[tid] = p / S;
    __syncthreads();
    if (tid < D_CLS) {
        float acc = c1b[tid];
#pragma unroll 8
        for (int d = 0; d < D_HID; d++)
            acc += pooled[d] * c1w[(size_t)d * D_CLS + tid];
        r1[tid] = fmaxf(acc, 0.f);
    }
    __syncthreads();
    if (tid < N_CLASSES) {
        float acc = c2b[tid];
#pragma unroll 8
        for (int j = 0; j < D_CLS; j++)
            acc += r1[j] * c2w[(size_t)j * N_CLASSES + tid];
        out[tid] = acc;
    }
}

extern "C" void kernel_launch(void* const* d_in, const int* in_sizes, int n_in,
                              void* d_out, int out_size, void* d_ws, size_t ws_size,
                              hipStream_t stream) {
    const float* xp  = (const float*)d_in[0];
    const float* w1  = (const float*)d_in[2];
    const float* b1  = (const float*)d_in[3];
    const float* wv  = (const float*)d_in[10];
    const float* bv  = (const float*)d_in[11];
    const float* wa  = (const float*)d_in[12];
    const float* ba  = (const float*)d_in[13];
    const float* wb  = (const float*)d_in[14];
    const float* bb  = (const float*)d_in[15];
    const float* acw = (const float*)d_in[16];
    const float* acb = (const float*)d_in[17];
    const float* c1w = (const float*)d_in[18];
    const float* c1b = (const float*)d_in[19];
    const float* c2w = (const float*)d_in[20];
    const float* c2b = (const float*)d_in[21];
    float* out = (float*)d_out;

    char* ws = (char*)d_ws;
    __hip_bfloat16* w1t = (__hip_bfloat16*)(ws);                 // 512 KB
    __hip_bfloat16* wvt = (__hip_bfloat16*)(ws + 524288);        // 128 KB
    __hip_bfloat16* wat = (__hip_bfloat16*)(ws + 655360);        // 128 KB
    __hip_bfloat16* wbt = (__hip_bfloat16*)(ws + 786432);        // 128 KB
    float* p1 = (float*)(ws + 917504);                           // 782*258*4 = 807,024 B
    float* p2 = (float*)(ws + 917504 + 807024);                  // 64*258*4 = 66,048 B

    hipLaunchKernelGGL(convert_weights, dim3(1024), dim3(256), 0, stream,
                       w1, wv, wa, wb, w1t, wvt, wat, wbt);
    hipLaunchKernelGGL(mcat_main, dim3(NBLK), dim3(256), 0, stream,
                       xp, w1t, b1, wvt, bv, wat, ba, wbt, bb, acw, acb, p1);
    hipLaunchKernelGGL(mcat_fin_a, dim3(NB2), dim3(256), 0, stream, p1, p2);
    hipLaunchKernelGGL(mcat_fin_b, dim3(1), dim3(256), 0, stream,
                       p2, c1w, c1b, c2w, c2b, out);
}